// Round 8
// baseline (711.320 us; speedup 1.0000x reference)
//
#include <hip/hip_runtime.h>
#include <hip/hip_bf16.h>
#include <math.h>

#define N_PTS 65534
#define GH 180
#define GW 360
#define NCELL (GH*GW)
#define PI_F 3.14159265358979323846f
#define NSEC 92

typedef __bf16 bf16;
typedef bf16 bf16x8 __attribute__((ext_vector_type(8)));
typedef bf16 bf16x4 __attribute__((ext_vector_type(4)));
typedef float f32x4 __attribute__((ext_vector_type(4)));

// wave-level LDS fence: drains LDS queue + compiler memory barrier (load-bearing).
#define LDS_FENCE() asm volatile("s_waitcnt lgkmcnt(0)" ::: "memory")

static __device__ __forceinline__ f32x4 mfma16(bf16x8 a, bf16x8 b, f32x4 c){
    return __builtin_amdgcn_mfma_f32_16x16x32_bf16(a,b,c,0,0,0);
}

// HW trig in revolutions: sin(2*pi*t) = v_sin(t), valid after fract. 4 VALU vs
// libm sinf's ~12-15 (software range reduction). Exact-pow2 scaling keeps the
// argument identical to the reference's f32 product.
static __device__ __forceinline__ float fsin_rev(float rev){
    float r = rev - floorf(rev);
    float o; asm("v_sin_f32 %0, %1" : "=v"(o) : "v"(r)); return o;
}
static __device__ __forceinline__ float fcos_rev(float rev){
    float r = rev - floorf(rev);
    float o; asm("v_cos_f32 %0, %1" : "=v"(o) : "v"(r)); return o;
}

// ---------------- repack all weights into the fragment-ordered stream.
// NOTE: Wq (QKV s3==0) is pre-scaled by 0.25*log2(e) so softmax can use exp2
// directly (fold moved here from the kernel).
__global__ void repack_kernel(const float* __restrict__ W_emb,
                              const float* __restrict__ Wqkv,
                              const float* __restrict__ Wo,
                              const float* __restrict__ Wf1,
                              const float* __restrict__ Wf2,
                              const float* __restrict__ W_comb,
                              bf16* __restrict__ stream){
    int idx = blockIdx.x*256 + threadIdx.x;
    if (idx >= NSEC*8192) return;
    int sec = idx >> 13;
    int r   = idx & 8191;
    int u   = r >> 9;
    int e   = r & 511;
    int l   = e >> 3, j = e & 7;
    int g   = l >> 4, c = l & 15;
    float v = 0.f;
    if (sec < 8){                                  // embed: sec=ch, u=nt*3+ks (12 used)
        if (u < 12){
            int nt=u/3, ks=u%3;
            int n = sec*64 + nt*16 + c;
            int k = ks*32 + g*8 + j;
            if (k < 75) v = W_emb[(size_t)k*512 + n];
        }
    } else if (sec < 60){                          // layers
        int lay = (sec-8)/26, s = (sec-8)%26;
        if (s < 8){                                // QKV: s=hd, u=s3*4+ks (12 used)
            if (u < 12){
                int s3=u/4, ks=u%4;
                int col = s3*128 + s*16 + c;
                int k = ks*32 + g*8 + j;
                v = Wqkv[(size_t)lay*49152 + (size_t)k*384 + col];
                if (s3==0) v *= 0.36067376f;       // 0.25*log2(e) fold
            }
        } else if (s < 10){                        // O: u=(nh&3)*4+ks
            int nh = (s-8)*4 + u/4, ks = u%4;
            int k = ks*32 + g*8 + j;
            v = Wo[(size_t)lay*16384 + (size_t)k*128 + nh*16 + c];
        } else {                                   // FFN: s-10 = ch*2 + (0:F1,1:F2)
            int t = s-10, ch = t>>1;
            if (!(t&1)){                           // F1: u=nt*4+ks
                int nt=u/4, ks=u%4;
                int n = ch*64 + nt*16 + c;
                int k = ks*32 + g*8 + j;
                v = Wf1[(size_t)lay*65536 + (size_t)k*512 + n];
            } else {                               // F2: u=nt2*2+ks
                int nt2=u/2, ks=u%2;
                int kk = ks*32 + g*8 + j;
                v = Wf2[(size_t)lay*65536 + (size_t)(ch*64+kk)*128 + nt2*16 + c];
            }
        }
    } else {                                       // comb: sec-60=chk, u=tk*4+ks
        int chk = sec-60, tk=u/4, ks=u%4;
        int n = chk*16 + c;
        int k = tk*128 + ks*32 + g*8 + j;
        v = W_comb[(size_t)k*512 + n];
    }
    stream[idx] = (bf16)v;
}

// ---------------- per-point grid index + counts
__global__ void count_kernel(const float* __restrict__ x, int* __restrict__ flat,
                             int* __restrict__ cnt){
    int p = blockIdx.x*256 + threadIdx.x;
    if (p >= N_PTS) return;
    float lat = x[p*24+0], lon = x[p*24+1];
    if (lat == -90.0f) lat += 1e-4f;
    int lati = (int)floorf(90.0f - lat);
    int loni = (180 + (int)floorf(lon + 180.0f)) % 360;
    lati = min(max(lati,0),GH-1);
    loni = min(max(loni,0),GW-1);
    int f = lati*GW + loni;
    flat[p] = f;
    atomicAdd(&cnt[f], 1);
}

// ---- register prefetch of weight fragments (global->VGPR, L2-resident stream).
#define LD12(F, sb) do{ _Pragma("unroll") for (int u=0;u<12;++u) (F)[u]=(sb)[u*64+l]; }while(0)
#define LD16(F, sb) do{ _Pragma("unroll") for (int u=0;u<16;++u) (F)[u]=(sb)[u*64+l]; }while(0)

// params in LDS (bf16): offsets
#define P_EMB  0
#define P_QKV  512
#define P_O    1280
#define P_F1   1536
#define P_F2   2560
#define P_L1S  2816
#define P_L1B  3072
#define P_L2S  3328
#define P_L2B  3584
#define P_CMB  3840

// ---------------- per-phase compute bodies (static register indexing throughout)
#define EMBED_BODY(CH, F) do{ \
    const int tk_ = (CH)>>1; \
    const int hn_ = ((CH)&1)*4; \
    _Pragma("unroll") \
    for (int nt=0; nt<4; ++nt){ \
        f32x4 acc = {0.f,0.f,0.f,0.f}; \
        _Pragma("unroll") \
        for (int ks=0;ks<3;++ks) acc = mfma16(afe[ks], (F)[nt*3+ks], acc); \
        float bb = (float)prm[P_EMB + (CH)*64 + nt*16 + c]; \
        h[0][hn_+nt][tk_] = acc[0] + bb; \
        h[1][hn_+nt][tk_] = acc[1] + bb; } \
}while(0)

// Zero-shuffle attention (A-frag and B-frag share the same lane mapping):
//  Q^T,K^T via swapped-operand mfma (C[ch 4g+r][tok c]); V normal (C[tok 4g+r][ch c]).
//  S^T = mfma(Kt,Qt): lane (g,c) regs r = S[query c][key 4g+r] -> IN-REGISTER softmax.
//  Valid only on lanes g==c>>2 (same point); others give cross-point scores -> P=0.
//  O^T = mfma(Vt,Pt): lane (g,c) regs r = O[tok c][ch hd*16+4g+r] -> one 8B tile write.
#define QKV_BODY(HD, F) do{ \
    float bqv[4], bkv[4]; \
    _Pragma("unroll") \
    for (int r=0;r<4;++r){ \
        bqv[r] = (float)prm[P_QKV + lay*384 +       (HD)*16 + 4*g + r]; \
        bkv[r] = (float)prm[P_QKV + lay*384 + 128 + (HD)*16 + 4*g + r]; } \
    float bv = (float)prm[P_QKV + lay*384 + 256 + (HD)*16 + c]; \
    _Pragma("unroll") \
    for (int mt=0;mt<2;++mt){ \
        f32x4 aq={0.f,0.f,0.f,0.f}, ak={0.f,0.f,0.f,0.f}, av={0.f,0.f,0.f,0.f}; \
        _Pragma("unroll") \
        for (int ks=0;ks<4;++ks){ \
            aq = mfma16((F)[ks],     af[mt][ks], aq); \
            ak = mfma16((F)[4+ks],   af[mt][ks], ak); \
            av = mfma16(af[mt][ks], (F)[8+ks],   av); } \
        bf16x8 qt, kt, vt; \
        _Pragma("unroll") \
        for (int r=0;r<4;++r){ \
            qt[r]=(bf16)(aq[r]+bqv[r]); qt[4+r]=(bf16)0.f; \
            kt[r]=(bf16)(ak[r]+bkv[r]); kt[4+r]=(bf16)0.f; \
            vt[r]=(bf16)(av[r]+bv);     vt[4+r]=(bf16)0.f; } \
        f32x4 st = mfma16(kt, qt, (f32x4){0.f,0.f,0.f,0.f}); \
        float m = fmaxf(fmaxf(st[0],st[1]),fmaxf(st[2],st[3])); \
        float e0=exp2f(st[0]-m), e1=exp2f(st[1]-m); \
        float e2=exp2f(st[2]-m), e3=exp2f(st[3]-m); \
        float inv = __builtin_amdgcn_rcpf(e0+e1+e2+e3); \
        float pm = pv ? inv : 0.f; \
        bf16x8 pt; \
        pt[0]=(bf16)(e0*pm); pt[1]=(bf16)(e1*pm); \
        pt[2]=(bf16)(e2*pm); pt[3]=(bf16)(e3*pm); \
        pt[4]=(bf16)0.f; pt[5]=(bf16)0.f; pt[6]=(bf16)0.f; pt[7]=(bf16)0.f; \
        f32x4 ot = mfma16(vt, pt, (f32x4){0.f,0.f,0.f,0.f}); \
        bf16x4 ow; \
        _Pragma("unroll") \
        for (int r=0;r<4;++r) ow[r]=(bf16)ot[r]; \
        *(bf16x4*)&tile[wv][mt*16+c][(HD)*16+4*g] = ow; \
    } \
}while(0)

#define O_BODY(S2, F) do{ \
    _Pragma("unroll") \
    for (int n4=0;n4<4;++n4){ \
        float bias = (float)prm[P_O + lay*128 + ((S2)*4+n4)*16 + c]; \
        _Pragma("unroll") \
        for (int mt=0;mt<2;++mt){ \
            f32x4 a = h[mt][(S2)*4+n4]; \
            _Pragma("unroll") \
            for (int ks=0;ks<4;++ks) a = mfma16(oa[mt][ks], (F)[n4*4+ks], a); \
            _Pragma("unroll") \
            for (int j=0;j<4;++j) a[j]+=bias; \
            h[mt][(S2)*4+n4]=a; } } \
}while(0)

#define F1_BODY(CH, F) do{ \
    _Pragma("unroll") \
    for (int nt=0;nt<4;++nt){ \
        float bias = (float)prm[P_F1 + lay*512 + (CH)*64 + nt*16 + c]; \
        _Pragma("unroll") \
        for (int mt=0;mt<2;++mt){ \
            f32x4 a = {0.f,0.f,0.f,0.f}; \
            _Pragma("unroll") \
            for (int ks=0;ks<4;++ks) a = mfma16(f1a[mt][ks], (F)[nt*4+ks], a); \
            _Pragma("unroll") \
            for (int j=0;j<4;++j){ \
                float xx = a[j]+bias; \
                float t2 = xx*xx; \
                float pp = fmaf(t2, 0.044715f, 1.0f); \
                float w2 = xx*pp; \
                float u  = exp2f(-2.3022082f*w2); \
                float r  = __builtin_amdgcn_rcpf(1.0f+u); \
                tile[wv][mt*16+g*4+j][nt*16+c] = (bf16)(xx*r); } } } \
}while(0)

#define F2_BODY(F) do{ \
    _Pragma("unroll") \
    for (int nt2=0;nt2<8;++nt2){ \
        _Pragma("unroll") \
        for (int mt=0;mt<2;++mt){ \
            f32x4 a = h[mt][nt2]; \
            _Pragma("unroll") \
            for (int ks=0;ks<2;++ks) a = mfma16(ga[mt][ks], (F)[nt2*2+ks], a); \
            h[mt][nt2]=a; } } \
}while(0)

// comb: 4 independent accumulators (one per tk) break the former 16-deep
// dependent MFMA chain (~16-20 cy dependent latency vs ~5 cy issue).
#define COMB_BODY(CHK, F) do{ \
    f32x4 ac0={0.f,0.f,0.f,0.f}, ac1={0.f,0.f,0.f,0.f}; \
    f32x4 ac2={0.f,0.f,0.f,0.f}, ac3={0.f,0.f,0.f,0.f}; \
    _Pragma("unroll") \
    for (int ks=0;ks<4;++ks){ \
        ac0 = mfma16(afc[0][ks], (F)[0*4+ks], ac0); \
        ac1 = mfma16(afc[1][ks], (F)[1*4+ks], ac1); \
        ac2 = mfma16(afc[2][ks], (F)[2*4+ks], ac2); \
        ac3 = mfma16(afc[3][ks], (F)[3*4+ks], ac3); } \
    f32x4 a; \
    _Pragma("unroll") \
    for (int r=0;r<4;++r) a[r] = (ac0[r]+ac1[r])+(ac2[r]+ac3[r]); \
    if (g<2){ \
        float bb = (float)prm[P_CMB + (CHK)*16+c]; \
        _Pragma("unroll") \
        for (int j=0;j<4;++j){ \
            int p = pb + g*4 + j; \
            if (p < N_PTS) \
                atomicAdd(&out[(size_t)flj[j]*512 + (CHK)*16 + c], (a[j]+bb)*ivj[j]); } } \
}while(0)

// ================= fully fused: features -> embed -> 2 layers -> comb -> scatter
// wave = 8 points = 32 tokens. Barrier-free (waves independent after prm fill).
// Weight sections prefetched global->VGPR one full compute-phase ahead (wA/wB).
__global__ __launch_bounds__(256,2) void fused_kernel(
    const float* __restrict__ x,
    const bf16* __restrict__ stream,
    const float* __restrict__ b_emb, const float* __restrict__ bqkv,
    const float* __restrict__ bo,    const float* __restrict__ bf1,
    const float* __restrict__ bf2,   const float* __restrict__ b_comb,
    const float* __restrict__ ln1s,  const float* __restrict__ ln1b,
    const float* __restrict__ ln2s,  const float* __restrict__ ln2b,
    const int* __restrict__ flat,    const int* __restrict__ cnt,
    float* __restrict__ out)
{
    __shared__ __align__(16) bf16  tile[4][32][136];  // per-wave transpose tile (34,816 B)
    __shared__ __align__(16) bf16  prm[4352];         // params (8,704 B)
    const int tid = threadIdx.x;
    const int wv = tid>>6, l = tid&63;
    const int g = l>>4, c = l&15;
    const bool pv = (g == (c>>2));   // same-point lane for in-register softmax
    const int pb = blockIdx.x*32 + wv*8;
    const bf16x8* gs8 = (const bf16x8*)stream;

    // ---- params -> LDS (bf16; exact for this problem's 0/1 affine params).
    // bqkv's Q part (first 128 of each layer's 384) pre-scaled to match Wq fold.
    for (int i=tid; i<4352; i+=256){
        float v;
        if      (i<512)  v=b_emb[i];
        else if (i<1280){ v=bqkv[i-512]; if (((i-512)%384) < 128) v *= 0.36067376f; }
        else if (i<1536) v=bo[i-1280];
        else if (i<2560) v=bf1[i-1536];
        else if (i<2816) v=bf2[i-2560];
        else if (i<3072) v=ln1s[i-2816];
        else if (i<3328) v=ln1b[i-3072];
        else if (i<3584) v=ln2s[i-3328];
        else if (i<3840) v=ln2b[i-3584];
        else             v=b_comb[i-3840];
        prm[i]=(bf16)v;
    }

    // ---- scatter indices
    int flj[4]; float ivj[4];
    #pragma unroll
    for (int j=0;j<4;++j){
        int p = pb + g*4 + j;
        if (g<2 && p<N_PTS){ int f=flat[p]; flj[j]=f;
            ivj[j]=__builtin_amdgcn_rcpf(fmaxf((float)cnt[f],1.f)); }
        else { flj[j]=0; ivj[j]=0.f; }
    }

    __syncthreads();                 // prm visible to all waves (the ONLY barrier)

    // ---- prefetch embed section 0 NOW; the trig-heavy feature phase hides it
    bf16x8 wA[16], wB[16];
    LD12(wA, gs8);

    // ---- features into tile (row remap; see round-3 notes)
    {
        const int pl = l>>3, w = l&7;
        const int p = pb + pl;
        const bool valid = (p < N_PTS);
        const int row  = (pl<4)? (pl*4)   : ((pl-4)*4+1);
        const int zrow = (pl<4)? (pl*4+2) : ((pl-4)*4+3);
        float lat=0.f, lon=0.f, t=0.f;
        if (valid){ lat=x[p*24+0]; lon=x[p*24+1]; t=x[p*24+2]; }
        if (lat == -90.0f) lat += 1e-4f;
        float pvs[3] = { -lat - floorf(-lat), lon - floorf(lon), t + 1.0f };
        #pragma unroll
        for (int i=0;i<12;++i){
            int f = w*12 + i;
            float val;
            if (f >= 75) val = 0.f;
            else if (f < 24){
                if (f==0)      val = lat*(1.f/90.f);
                else if (f==1) val = lon*(1.f/180.f);
                else if (f==2) val = t*(1.f/12.f);
                else           val = valid ? x[p*24+f] : 0.f;
            } else if (f<27) val = pvs[f-24];
            else if (f<51){ int q=f-27; val = fsin_rev(pvs[q>>3]*(float)(1<<(q&7))*0.5f); }
            else          { int q=f-51; val = fcos_rev(pvs[q>>3]*(float)(1<<(q&7))*0.5f); }
            if (!valid) val = 0.f;
            tile[wv][row][f]  = (bf16)val;
            tile[wv][zrow][f] = (bf16)0.f;
        }
    }
    LDS_FENCE();                     // feature writes -> afe reads
    bf16x8 afe[3];
    #pragma unroll
    for (int ks=0;ks<3;++ks) afe[ks] = *(const bf16x8*)&tile[wv][c][ks*32+g*8];

    f32x4 h[2][8];
    // ---- embed: 8 sections, prefetch s+1 during compute of s
    #pragma unroll
    for (int chp=0; chp<4; ++chp){
        const int ch = chp*2;
        LD12(wB, gs8 + (size_t)(ch+1)*1024);
        EMBED_BODY(ch, wA);
        if (ch+2 < 8) LD12(wA, gs8 + (size_t)(ch+2)*1024);
        else          LD12(wA, gs8 + (size_t)8*1024);     // chain: QKV lay0 hd0
        EMBED_BODY(ch+1, wB);
    }

    // ---- transformer layers
    for (int lay=0; lay<2; ++lay){
        float ls[8], lb[8];
        // ===== LN1 -> tile (hides the QKV-sec0 prefetch issued at prior phase tail)
        #pragma unroll
        for (int n=0;n<8;++n){ ls[n]=(float)prm[P_L1S+lay*128+n*16+c]; lb[n]=(float)prm[P_L1B+lay*128+n*16+c]; }
        #pragma unroll
        for (int mt=0;mt<2;++mt)
            #pragma unroll
            for (int j=0;j<4;++j){
                float s=0.f,q=0.f;
                #pragma unroll
                for (int n=0;n<8;++n){ float v=h[mt][n][j]; s+=v; q+=v*v; }
                s += __shfl_xor(s,1); s += __shfl_xor(s,2); s += __shfl_xor(s,4); s += __shfl_xor(s,8);
                q += __shfl_xor(q,1); q += __shfl_xor(q,2); q += __shfl_xor(q,4); q += __shfl_xor(q,8);
                float m = s*(1.f/128.f);
                float var = q*(1.f/128.f) - m*m;
                float rs = rsqrtf(var + 1e-5f);
                #pragma unroll
                for (int n=0;n<8;++n)
                    tile[wv][mt*16+g*4+j][n*16+c] = (bf16)((h[mt][n][j]-m)*rs*ls[n]+lb[n]);
            }
        LDS_FENCE();                 // LN1 writes -> af reads
        bf16x8 af[2][4];
        #pragma unroll
        for (int mt=0;mt<2;++mt)
            #pragma unroll
            for (int ks=0;ks<4;++ks)
                af[mt][ks] = *(const bf16x8*)&tile[wv][mt*16+c][ks*32+g*8];
        LDS_FENCE();                 // af reads -> ot writes (WAR)
        // ===== QKV + zero-shuffle attention: 8 sections, prefetch s+1 during s
        for (int hdp=0; hdp<4; ++hdp){
            const int hd = hdp*2;
            LD12(wB, gs8 + (size_t)(8 + lay*26 + hd+1)*1024);
            QKV_BODY(hd, wA);
            if (hd+2 < 8) LD12(wA, gs8 + (size_t)(8 + lay*26 + hd+2)*1024);
            else          LD16(wA, gs8 + (size_t)(8 + lay*26 + 8)*1024);   // chain: O sec0
            QKV_BODY(hd+1, wB);
        }
        LDS_FENCE();                 // ot writes -> oa reads
        // ===== O-proj (2 sections), residual accumulates in h
        bf16x8 oa[2][4];
        #pragma unroll
        for (int mt=0;mt<2;++mt)
            #pragma unroll
            for (int ks=0;ks<4;++ks)
                oa[mt][ks] = *(const bf16x8*)&tile[wv][mt*16+c][ks*32+g*8];
        LDS_FENCE();                 // oa reads -> LN2 writes (WAR)
        LD16(wB, gs8 + (size_t)(8 + lay*26 + 9)*1024);    // O sec1
        O_BODY(0, wA);
        LD16(wA, gs8 + (size_t)(8 + lay*26 + 10)*1024);   // chain: F1 ch0 (hidden by LN2)
        O_BODY(1, wB);
        // ===== LN2 -> tile
        #pragma unroll
        for (int n=0;n<8;++n){ ls[n]=(float)prm[P_L2S+lay*128+n*16+c]; lb[n]=(float)prm[P_L2B+lay*128+n*16+c]; }
        #pragma unroll
        for (int mt=0;mt<2;++mt)
            #pragma unroll
            for (int j=0;j<4;++j){
                float s=0.f,q=0.f;
                #pragma unroll
                for (int n=0;n<8;++n){ float v=h[mt][n][j]; s+=v; q+=v*v; }
                s += __shfl_xor(s,1); s += __shfl_xor(s,2); s += __shfl_xor(s,4); s += __shfl_xor(s,8);
                q += __shfl_xor(q,1); q += __shfl_xor(q,2); q += __shfl_xor(q,4); q += __shfl_xor(q,8);
                float m = s*(1.f/128.f);
                float var = q*(1.f/128.f) - m*m;
                float rs = rsqrtf(var + 1e-5f);
                #pragma unroll
                for (int n=0;n<8;++n)
                    tile[wv][mt*16+g*4+j][n*16+c] = (bf16)((h[mt][n][j]-m)*rs*ls[n]+lb[n]);
            }
        LDS_FENCE();                 // LN2 writes -> f1a reads
        bf16x8 f1a[2][4];
        #pragma unroll
        for (int mt=0;mt<2;++mt)
            #pragma unroll
            for (int ks=0;ks<4;++ks)
                f1a[mt][ks] = *(const bf16x8*)&tile[wv][mt*16+c][ks*32+g*8];
        LDS_FENCE();                 // f1a reads -> gt writes (WAR)
        // ===== FFN: per ch {F2 prefetch, F1+GELU, ga, next-F1 prefetch, F2}
        const bf16x8* nxsec = gs8 + (size_t)((lay==0) ? (8+26) : 60)*1024;
        bf16x8 ga[2][2];
        for (int ch=0; ch<8; ++ch){
            LD16(wB, gs8 + (size_t)(8 + lay*26 + 10 + ch*2 + 1)*1024);  // F2[ch]
            F1_BODY(ch, wA);
            LDS_FENCE();             // gt writes -> ga reads
            #pragma unroll
            for (int mt=0;mt<2;++mt)
                #pragma unroll
                for (int ks=0;ks<2;++ks)
                    ga[mt][ks] = *(const bf16x8*)&tile[wv][mt*16+c][ks*32+g*8];
            LDS_FENCE();             // ga reads -> next gt writes (WAR)
            if (ch < 7) LD16(wA, gs8 + (size_t)(8 + lay*26 + 10 + (ch+1)*2)*1024);
            else        LD16(wA, nxsec);   // chain: next layer QKV0 / comb0
            F2_BODY(wB);
        }
        #pragma unroll
        for (int nt2=0;nt2<8;++nt2){
            float bias = (float)prm[P_F2 + lay*128 + nt2*16+c];
            #pragma unroll
            for (int mt=0;mt<2;++mt)
                #pragma unroll
                for (int j=0;j<4;++j) h[mt][nt2][j]+=bias;
        }
    }

    // ---- comb + scatter-mean (wA = sec60, prefetched at lay1 FFN tail)
    #pragma unroll
    for (int mt=0;mt<2;++mt)
        #pragma unroll
        for (int n=0;n<8;++n)
            #pragma unroll
            for (int j=0;j<4;++j)
                tile[wv][mt*16+g*4+j][n*16+c] = (bf16)h[mt][n][j];
    LDS_FENCE();                     // h writes -> afc reads
    bf16x8 afc[4][4];
    #pragma unroll
    for (int tk=0;tk<4;++tk)
        #pragma unroll
        for (int ks=0;ks<4;++ks)
            afc[tk][ks] = *(const bf16x8*)&tile[wv][(c&7)*4+tk][ks*32+g*8];
    for (int kp=0; kp<16; ++kp){
        const int chk = kp*2;
        LD16(wB, gs8 + (size_t)(60 + chk + 1)*1024);
        COMB_BODY(chk, wA);
        if (chk+2 < 32) LD16(wA, gs8 + (size_t)(60 + chk + 2)*1024);
        COMB_BODY(chk+1, wB);
    }
}

extern "C" void kernel_launch(void* const* d_in, const int* in_sizes, int n_in,
                              void* d_out, int out_size, void* d_ws, size_t ws_size,
                              hipStream_t stream){
    (void)in_sizes; (void)n_in; (void)ws_size;
    const float* x      = (const float*)d_in[0];
    const float* W_emb  = (const float*)d_in[1];
    const float* b_emb  = (const float*)d_in[2];
    const float* ln1_s  = (const float*)d_in[3];
    const float* ln1_b  = (const float*)d_in[4];
    const float* Wqkv   = (const float*)d_in[5];
    const float* bqkv   = (const float*)d_in[6];
    const float* Wo     = (const float*)d_in[7];
    const float* bo     = (const float*)d_in[8];
    const float* ln2_s  = (const float*)d_in[9];
    const float* ln2_b  = (const float*)d_in[10];
    const float* Wf1    = (const float*)d_in[11];
    const float* bf1    = (const float*)d_in[12];
    const float* Wf2    = (const float*)d_in[13];
    const float* bf2    = (const float*)d_in[14];
    const float* W_comb = (const float*)d_in[15];
    const float* b_comb = (const float*)d_in[16];
    float* out = (float*)d_out;

    char* ws = (char*)d_ws;
    size_t off = 0;
    auto alloc = [&](size_t bytes)->char*{
        char* p = ws + off; off = (off + bytes + 255) & ~(size_t)255; return p;
    };
    bf16* wstream = (bf16*) alloc((size_t)NSEC*8192*2);
    int*  flat    = (int*)  alloc((size_t)N_PTS*4);
    int*  cnt     = (int*)  alloc((size_t)NCELL*4);

    hipMemsetAsync(d_out, 0, (size_t)out_size*sizeof(float), stream);
    hipMemsetAsync(cnt, 0, (size_t)NCELL*4, stream);

    repack_kernel<<<(NSEC*8192+255)/256, 256, 0, stream>>>(
        W_emb, Wqkv, Wo, Wf1, Wf2, W_comb, wstream);
    count_kernel<<<(N_PTS+255)/256, 256, 0, stream>>>(x, flat, cnt);

    fused_kernel<<<2048, 256, 0, stream>>>(x, wstream,
        b_emb, bqkv, bo, bf1, bf2, b_comb,
        ln1_s, ln1_b, ln2_s, ln2_b, flat, cnt, out);
}

// Round 10
// 691.482 us; speedup vs baseline: 1.0287x; 1.0287x over previous
//
#include <hip/hip_runtime.h>
#include <hip/hip_bf16.h>
#include <math.h>

#define N_PTS 65534
#define GH 180
#define GW 360
#define NCELL (GH*GW)
#define PI_F 3.14159265358979323846f
#define NSEC 92

typedef __bf16 bf16;
typedef bf16 bf16x8 __attribute__((ext_vector_type(8)));
typedef bf16 bf16x4 __attribute__((ext_vector_type(4)));
typedef float f32x4 __attribute__((ext_vector_type(4)));

// wave-level LDS fence: drains LDS queue + compiler memory barrier (load-bearing).
#define LDS_FENCE() asm volatile("s_waitcnt lgkmcnt(0)" ::: "memory")
// raw barrier, NO waitcnt: used purely to time-align the block's 4 waves so
// their identical weight-stream loads coalesce in L1/MSHR (no data crosses waves).
#define RAW_BAR()   asm volatile("s_barrier" ::: "memory")

static __device__ __forceinline__ f32x4 mfma16(bf16x8 a, bf16x8 b, f32x4 c){
    return __builtin_amdgcn_mfma_f32_16x16x32_bf16(a,b,c,0,0,0);
}

// HW trig in revolutions: sin(2*pi*t) = v_sin(t), valid after fract. 4 VALU vs
// libm sinf's ~12-15 (software range reduction).
static __device__ __forceinline__ float fsin_rev(float rev){
    float r = rev - floorf(rev);
    float o; asm("v_sin_f32 %0, %1" : "=v"(o) : "v"(r)); return o;
}
static __device__ __forceinline__ float fcos_rev(float rev){
    float r = rev - floorf(rev);
    float o; asm("v_cos_f32 %0, %1" : "=v"(o) : "v"(r)); return o;
}

// ---------------- repack all weights into the fragment-ordered stream.
// NOTE: Wq (QKV s3==0) is pre-scaled by 0.25*log2(e) so softmax can use exp2
// directly (fold moved here from the kernel).
__global__ void repack_kernel(const float* __restrict__ W_emb,
                              const float* __restrict__ Wqkv,
                              const float* __restrict__ Wo,
                              const float* __restrict__ Wf1,
                              const float* __restrict__ Wf2,
                              const float* __restrict__ W_comb,
                              bf16* __restrict__ stream){
    int idx = blockIdx.x*256 + threadIdx.x;
    if (idx >= NSEC*8192) return;
    int sec = idx >> 13;
    int r   = idx & 8191;
    int u   = r >> 9;
    int e   = r & 511;
    int l   = e >> 3, j = e & 7;
    int g   = l >> 4, c = l & 15;
    float v = 0.f;
    if (sec < 8){                                  // embed: sec=ch, u=nt*3+ks (12 used)
        if (u < 12){
            int nt=u/3, ks=u%3;
            int n = sec*64 + nt*16 + c;
            int k = ks*32 + g*8 + j;
            if (k < 75) v = W_emb[(size_t)k*512 + n];
        }
    } else if (sec < 60){                          // layers
        int lay = (sec-8)/26, s = (sec-8)%26;
        if (s < 8){                                // QKV: s=hd, u=s3*4+ks (12 used)
            if (u < 12){
                int s3=u/4, ks=u%4;
                int col = s3*128 + s*16 + c;
                int k = ks*32 + g*8 + j;
                v = Wqkv[(size_t)lay*49152 + (size_t)k*384 + col];
                if (s3==0) v *= 0.36067376f;       // 0.25*log2(e) fold
            }
        } else if (s < 10){                        // O: u=(nh&3)*4+ks
            int nh = (s-8)*4 + u/4, ks = u%4;
            int k = ks*32 + g*8 + j;
            v = Wo[(size_t)lay*16384 + (size_t)k*128 + nh*16 + c];
        } else {                                   // FFN: s-10 = ch*2 + (0:F1,1:F2)
            int t = s-10, ch = t>>1;
            if (!(t&1)){                           // F1: u=nt*4+ks
                int nt=u/4, ks=u%4;
                int n = ch*64 + nt*16 + c;
                int k = ks*32 + g*8 + j;
                v = Wf1[(size_t)lay*65536 + (size_t)k*512 + n];
            } else {                               // F2: u=nt2*2+ks
                int nt2=u/2, ks=u%2;
                int kk = ks*32 + g*8 + j;
                v = Wf2[(size_t)lay*65536 + (size_t)(ch*64+kk)*128 + nt2*16 + c];
            }
        }
    } else {                                       // comb: sec-60=chk, u=tk*4+ks
        int chk = sec-60, tk=u/4, ks=u%4;
        int n = chk*16 + c;
        int k = tk*128 + ks*32 + g*8 + j;
        v = W_comb[(size_t)k*512 + n];
    }
    stream[idx] = (bf16)v;
}

// ---------------- per-point grid index + counts
__global__ void count_kernel(const float* __restrict__ x, int* __restrict__ flat,
                             int* __restrict__ cnt){
    int p = blockIdx.x*256 + threadIdx.x;
    if (p >= N_PTS) return;
    float lat = x[p*24+0], lon = x[p*24+1];
    if (lat == -90.0f) lat += 1e-4f;
    int lati = (int)floorf(90.0f - lat);
    int loni = (180 + (int)floorf(lon + 180.0f)) % 360;
    lati = min(max(lati,0),GH-1);
    loni = min(max(loni,0),GW-1);
    int f = lati*GW + loni;
    flat[p] = f;
    atomicAdd(&cnt[f], 1);
}

// ---- register prefetch of weight fragments (global->VGPR, L2-resident stream).
#define LD12(F, sb) do{ _Pragma("unroll") for (int u=0;u<12;++u) (F)[u]=(sb)[u*64+l]; }while(0)
#define LD16(F, sb) do{ _Pragma("unroll") for (int u=0;u<16;++u) (F)[u]=(sb)[u*64+l]; }while(0)

// params in LDS (bf16): offsets
#define P_EMB  0
#define P_QKV  512
#define P_O    1280
#define P_F1   1536
#define P_F2   2560
#define P_L1S  2816
#define P_L1B  3072
#define P_L2S  3328
#define P_L2B  3584
#define P_CMB  3840

// ---------------- per-phase compute bodies (static register indexing throughout)
#define EMBED_BODY(CH, F) do{ \
    const int tk_ = (CH)>>1; \
    const int hn_ = ((CH)&1)*4; \
    _Pragma("unroll") \
    for (int nt=0; nt<4; ++nt){ \
        f32x4 acc = {0.f,0.f,0.f,0.f}; \
        _Pragma("unroll") \
        for (int ks=0;ks<3;++ks) acc = mfma16(afe[ks], (F)[nt*3+ks], acc); \
        float bb = (float)prm[P_EMB + (CH)*64 + nt*16 + c]; \
        h[0][hn_+nt][tk_] = acc[0] + bb; \
        h[1][hn_+nt][tk_] = acc[1] + bb; } \
}while(0)

// Zero-shuffle attention (A-frag and B-frag share the same lane mapping):
//  Q^T,K^T via swapped-operand mfma (C[ch 4g+r][tok c]); V normal (C[tok 4g+r][ch c]).
//  S^T = mfma(Kt,Qt): lane (g,c) regs r = S[query c][key 4g+r] -> IN-REGISTER softmax.
//  Valid only on lanes g==c>>2 (same point); others give cross-point scores -> P=0.
//  O^T = mfma(Vt,Pt): lane (g,c) regs r = O[tok c][ch hd*16+4g+r] -> one 8B tile write.
#define QKV_BODY(HD, F) do{ \
    float bqv[4], bkv[4]; \
    _Pragma("unroll") \
    for (int r=0;r<4;++r){ \
        bqv[r] = (float)prm[P_QKV + lay*384 +       (HD)*16 + 4*g + r]; \
        bkv[r] = (float)prm[P_QKV + lay*384 + 128 + (HD)*16 + 4*g + r]; } \
    float bv = (float)prm[P_QKV + lay*384 + 256 + (HD)*16 + c]; \
    _Pragma("unroll") \
    for (int mt=0;mt<2;++mt){ \
        f32x4 aq={0.f,0.f,0.f,0.f}, ak={0.f,0.f,0.f,0.f}, av={0.f,0.f,0.f,0.f}; \
        _Pragma("unroll") \
        for (int ks=0;ks<4;++ks){ \
            aq = mfma16((F)[ks],     af[mt][ks], aq); \
            ak = mfma16((F)[4+ks],   af[mt][ks], ak); \
            av = mfma16(af[mt][ks], (F)[8+ks],   av); } \
        bf16x8 qt, kt, vt; \
        _Pragma("unroll") \
        for (int r=0;r<4;++r){ \
            qt[r]=(bf16)(aq[r]+bqv[r]); qt[4+r]=(bf16)0.f; \
            kt[r]=(bf16)(ak[r]+bkv[r]); kt[4+r]=(bf16)0.f; \
            vt[r]=(bf16)(av[r]+bv);     vt[4+r]=(bf16)0.f; } \
        f32x4 st = mfma16(kt, qt, (f32x4){0.f,0.f,0.f,0.f}); \
        float m = fmaxf(fmaxf(st[0],st[1]),fmaxf(st[2],st[3])); \
        float e0=exp2f(st[0]-m), e1=exp2f(st[1]-m); \
        float e2=exp2f(st[2]-m), e3=exp2f(st[3]-m); \
        float inv = __builtin_amdgcn_rcpf(e0+e1+e2+e3); \
        float pm = pv ? inv : 0.f; \
        bf16x8 pt; \
        pt[0]=(bf16)(e0*pm); pt[1]=(bf16)(e1*pm); \
        pt[2]=(bf16)(e2*pm); pt[3]=(bf16)(e3*pm); \
        pt[4]=(bf16)0.f; pt[5]=(bf16)0.f; pt[6]=(bf16)0.f; pt[7]=(bf16)0.f; \
        f32x4 ot = mfma16(vt, pt, (f32x4){0.f,0.f,0.f,0.f}); \
        bf16x4 ow; \
        _Pragma("unroll") \
        for (int r=0;r<4;++r) ow[r]=(bf16)ot[r]; \
        *(bf16x4*)&tile[wv][mt*16+c][(HD)*16+4*g] = ow; \
    } \
}while(0)

#define O_BODY(S2, F) do{ \
    _Pragma("unroll") \
    for (int n4=0;n4<4;++n4){ \
        float bias = (float)prm[P_O + lay*128 + ((S2)*4+n4)*16 + c]; \
        _Pragma("unroll") \
        for (int mt=0;mt<2;++mt){ \
            f32x4 a = h[mt][(S2)*4+n4]; \
            _Pragma("unroll") \
            for (int ks=0;ks<4;++ks) a = mfma16(oa[mt][ks], (F)[n4*4+ks], a); \
            _Pragma("unroll") \
            for (int j=0;j<4;++j) a[j]+=bias; \
            h[mt][(S2)*4+n4]=a; } } \
}while(0)

#define F1_BODY(CH, F) do{ \
    _Pragma("unroll") \
    for (int nt=0;nt<4;++nt){ \
        float bias = (float)prm[P_F1 + lay*512 + (CH)*64 + nt*16 + c]; \
        _Pragma("unroll") \
        for (int mt=0;mt<2;++mt){ \
            f32x4 a = {0.f,0.f,0.f,0.f}; \
            _Pragma("unroll") \
            for (int ks=0;ks<4;++ks) a = mfma16(f1a[mt][ks], (F)[nt*4+ks], a); \
            _Pragma("unroll") \
            for (int j=0;j<4;++j){ \
                float xx = a[j]+bias; \
                float t2 = xx*xx; \
                float pp = fmaf(t2, 0.044715f, 1.0f); \
                float w2 = xx*pp; \
                float u  = exp2f(-2.3022082f*w2); \
                float r  = __builtin_amdgcn_rcpf(1.0f+u); \
                tile[wv][mt*16+g*4+j][nt*16+c] = (bf16)(xx*r); } } } \
}while(0)

#define F2_BODY(F) do{ \
    _Pragma("unroll") \
    for (int nt2=0;nt2<8;++nt2){ \
        _Pragma("unroll") \
        for (int mt=0;mt<2;++mt){ \
            f32x4 a = h[mt][nt2]; \
            _Pragma("unroll") \
            for (int ks=0;ks<2;++ks) a = mfma16(ga[mt][ks], (F)[nt2*2+ks], a); \
            h[mt][nt2]=a; } } \
}while(0)

// comb: SERIAL 16-deep chain on purpose (r7 form). The long dependent chain
// covers the vmcnt FIFO wait that includes this iteration's atomics (vmcnt
// retires in order; splitting the chain exposed ~600-1000cy atomic latency, r8).
// r9 bug fixed: atomic target must use the macro parameter (CHK), not the
// call-site variable chk (odd channel-blocks were written to even slots).
#define COMB_BODY(CHK, F) do{ \
    f32x4 a = {0.f,0.f,0.f,0.f}; \
    _Pragma("unroll") \
    for (int tk=0;tk<4;++tk) \
        _Pragma("unroll") \
        for (int ks=0;ks<4;++ks) a = mfma16(afc[tk][ks], (F)[tk*4+ks], a); \
    if (g<2){ \
        float bb = (float)prm[P_CMB + (CHK)*16+c]; \
        _Pragma("unroll") \
        for (int j=0;j<4;++j){ \
            int p = pb + g*4 + j; \
            if (p < N_PTS) \
                atomicAdd(&out[(size_t)flj[j]*512 + (CHK)*16 + c], (a[j]+bb)*ivj[j]); } } \
}while(0)

// ================= fully fused: features -> embed -> 2 layers -> comb -> scatter
// wave = 8 points = 32 tokens. Phase-top RAW_BAR()s align the block's waves so
// their identical stream loads hit L1/MSHR instead of 4x separate L2 trips.
__global__ __launch_bounds__(256,2) void fused_kernel(
    const float* __restrict__ x,
    const bf16* __restrict__ stream,
    const float* __restrict__ b_emb, const float* __restrict__ bqkv,
    const float* __restrict__ bo,    const float* __restrict__ bf1,
    const float* __restrict__ bf2,   const float* __restrict__ b_comb,
    const float* __restrict__ ln1s,  const float* __restrict__ ln1b,
    const float* __restrict__ ln2s,  const float* __restrict__ ln2b,
    const int* __restrict__ flat,    const int* __restrict__ cnt,
    float* __restrict__ out)
{
    __shared__ __align__(16) bf16  tile[4][32][136];  // per-wave transpose tile (34,816 B)
    __shared__ __align__(16) bf16  prm[4352];         // params (8,704 B)
    const int tid = threadIdx.x;
    const int wv = tid>>6, l = tid&63;
    const int g = l>>4, c = l&15;
    const bool pv = (g == (c>>2));   // same-point lane for in-register softmax
    const int pb = blockIdx.x*32 + wv*8;
    const bf16x8* gs8 = (const bf16x8*)stream;

    // ---- params -> LDS (bf16; exact for this problem's 0/1 affine params).
    // bqkv's Q part (first 128 of each layer's 384) pre-scaled to match Wq fold.
    for (int i=tid; i<4352; i+=256){
        float v;
        if      (i<512)  v=b_emb[i];
        else if (i<1280){ v=bqkv[i-512]; if (((i-512)%384) < 128) v *= 0.36067376f; }
        else if (i<1536) v=bo[i-1280];
        else if (i<2560) v=bf1[i-1536];
        else if (i<2816) v=bf2[i-2560];
        else if (i<3072) v=ln1s[i-2816];
        else if (i<3328) v=ln1b[i-3072];
        else if (i<3584) v=ln2s[i-3328];
        else if (i<3840) v=ln2b[i-3584];
        else             v=b_comb[i-3840];
        prm[i]=(bf16)v;
    }

    // ---- scatter indices
    int flj[4]; float ivj[4];
    #pragma unroll
    for (int j=0;j<4;++j){
        int p = pb + g*4 + j;
        if (g<2 && p<N_PTS){ int f=flat[p]; flj[j]=f;
            ivj[j]=__builtin_amdgcn_rcpf(fmaxf((float)cnt[f],1.f)); }
        else { flj[j]=0; ivj[j]=0.f; }
    }

    __syncthreads();                 // prm visible to all waves

    // ---- prefetch embed section 0 NOW; the trig-heavy feature phase hides it
    bf16x8 wA[16], wB[16];
    LD12(wA, gs8);

    // ---- features into tile (row remap; see round-3 notes)
    {
        const int pl = l>>3, w = l&7;
        const int p = pb + pl;
        const bool valid = (p < N_PTS);
        const int row  = (pl<4)? (pl*4)   : ((pl-4)*4+1);
        const int zrow = (pl<4)? (pl*4+2) : ((pl-4)*4+3);
        float lat=0.f, lon=0.f, t=0.f;
        if (valid){ lat=x[p*24+0]; lon=x[p*24+1]; t=x[p*24+2]; }
        if (lat == -90.0f) lat += 1e-4f;
        float pvs[3] = { -lat - floorf(-lat), lon - floorf(lon), t + 1.0f };
        #pragma unroll
        for (int i=0;i<12;++i){
            int f = w*12 + i;
            float val;
            if (f >= 75) val = 0.f;
            else if (f < 24){
                if (f==0)      val = lat*(1.f/90.f);
                else if (f==1) val = lon*(1.f/180.f);
                else if (f==2) val = t*(1.f/12.f);
                else           val = valid ? x[p*24+f] : 0.f;
            } else if (f<27) val = pvs[f-24];
            else if (f<51){ int q=f-27; val = fsin_rev(pvs[q>>3]*(float)(1<<(q&7))*0.5f); }
            else          { int q=f-51; val = fcos_rev(pvs[q>>3]*(float)(1<<(q&7))*0.5f); }
            if (!valid) val = 0.f;
            tile[wv][row][f]  = (bf16)val;
            tile[wv][zrow][f] = (bf16)0.f;
        }
    }
    LDS_FENCE();                     // feature writes -> afe reads
    bf16x8 afe[3];
    #pragma unroll
    for (int ks=0;ks<3;++ks) afe[ks] = *(const bf16x8*)&tile[wv][c][ks*32+g*8];

    f32x4 h[2][8];
    // ---- embed: 8 sections, prefetch s+1 during compute of s
    RAW_BAR();                       // align waves: stream loads coalesce in L1
    #pragma unroll
    for (int chp=0; chp<4; ++chp){
        const int ch = chp*2;
        LD12(wB, gs8 + (size_t)(ch+1)*1024);
        EMBED_BODY(ch, wA);
        if (ch+2 < 8) LD12(wA, gs8 + (size_t)(ch+2)*1024);
        else          LD12(wA, gs8 + (size_t)8*1024);     // chain: QKV lay0 hd0
        EMBED_BODY(ch+1, wB);
    }

    // ---- transformer layers
    for (int lay=0; lay<2; ++lay){
        float ls[8], lb[8];
        // ===== LN1 -> tile (hides the QKV-sec0 prefetch issued at prior phase tail)
        #pragma unroll
        for (int n=0;n<8;++n){ ls[n]=(float)prm[P_L1S+lay*128+n*16+c]; lb[n]=(float)prm[P_L1B+lay*128+n*16+c]; }
        #pragma unroll
        for (int mt=0;mt<2;++mt)
            #pragma unroll
            for (int j=0;j<4;++j){
                float s=0.f,q=0.f;
                #pragma unroll
                for (int n=0;n<8;++n){ float v=h[mt][n][j]; s+=v; q+=v*v; }
                s += __shfl_xor(s,1); s += __shfl_xor(s,2); s += __shfl_xor(s,4); s += __shfl_xor(s,8);
                q += __shfl_xor(q,1); q += __shfl_xor(q,2); q += __shfl_xor(q,4); q += __shfl_xor(q,8);
                float m = s*(1.f/128.f);
                float var = q*(1.f/128.f) - m*m;
                float rs = rsqrtf(var + 1e-5f);
                #pragma unroll
                for (int n=0;n<8;++n)
                    tile[wv][mt*16+g*4+j][n*16+c] = (bf16)((h[mt][n][j]-m)*rs*ls[n]+lb[n]);
            }
        LDS_FENCE();                 // LN1 writes -> af reads
        bf16x8 af[2][4];
        #pragma unroll
        for (int mt=0;mt<2;++mt)
            #pragma unroll
            for (int ks=0;ks<4;++ks)
                af[mt][ks] = *(const bf16x8*)&tile[wv][mt*16+c][ks*32+g*8];
        LDS_FENCE();                 // af reads -> ot writes (WAR)
        // ===== QKV + zero-shuffle attention: 8 sections, prefetch s+1 during s
        RAW_BAR();                   // re-align after LN drift
        for (int hdp=0; hdp<4; ++hdp){
            const int hd = hdp*2;
            LD12(wB, gs8 + (size_t)(8 + lay*26 + hd+1)*1024);
            QKV_BODY(hd, wA);
            if (hd+2 < 8) LD12(wA, gs8 + (size_t)(8 + lay*26 + hd+2)*1024);
            else          LD16(wA, gs8 + (size_t)(8 + lay*26 + 8)*1024);   // chain: O sec0
            QKV_BODY(hd+1, wB);
        }
        LDS_FENCE();                 // ot writes -> oa reads
        // ===== O-proj (2 sections), residual accumulates in h
        bf16x8 oa[2][4];
        #pragma unroll
        for (int mt=0;mt<2;++mt)
            #pragma unroll
            for (int ks=0;ks<4;++ks)
                oa[mt][ks] = *(const bf16x8*)&tile[wv][mt*16+c][ks*32+g*8];
        LDS_FENCE();                 // oa reads -> LN2 writes (WAR)
        LD16(wB, gs8 + (size_t)(8 + lay*26 + 9)*1024);    // O sec1
        O_BODY(0, wA);
        LD16(wA, gs8 + (size_t)(8 + lay*26 + 10)*1024);   // chain: F1 ch0 (hidden by LN2)
        O_BODY(1, wB);
        // ===== LN2 -> tile
        #pragma unroll
        for (int n=0;n<8;++n){ ls[n]=(float)prm[P_L2S+lay*128+n*16+c]; lb[n]=(float)prm[P_L2B+lay*128+n*16+c]; }
        #pragma unroll
        for (int mt=0;mt<2;++mt)
            #pragma unroll
            for (int j=0;j<4;++j){
                float s=0.f,q=0.f;
                #pragma unroll
                for (int n=0;n<8;++n){ float v=h[mt][n][j]; s+=v; q+=v*v; }
                s += __shfl_xor(s,1); s += __shfl_xor(s,2); s += __shfl_xor(s,4); s += __shfl_xor(s,8);
                q += __shfl_xor(q,1); q += __shfl_xor(q,2); q += __shfl_xor(q,4); q += __shfl_xor(q,8);
                float m = s*(1.f/128.f);
                float var = q*(1.f/128.f) - m*m;
                float rs = rsqrtf(var + 1e-5f);
                #pragma unroll
                for (int n=0;n<8;++n)
                    tile[wv][mt*16+g*4+j][n*16+c] = (bf16)((h[mt][n][j]-m)*rs*ls[n]+lb[n]);
            }
        LDS_FENCE();                 // LN2 writes -> f1a reads
        bf16x8 f1a[2][4];
        #pragma unroll
        for (int mt=0;mt<2;++mt)
            #pragma unroll
            for (int ks=0;ks<4;++ks)
                f1a[mt][ks] = *(const bf16x8*)&tile[wv][mt*16+c][ks*32+g*8];
        LDS_FENCE();                 // f1a reads -> gt writes (WAR)
        // ===== FFN: per ch {F2 prefetch, F1+GELU, ga, next-F1 prefetch, F2}
        RAW_BAR();                   // re-align for the 16-section FFN stream
        const bf16x8* nxsec = gs8 + (size_t)((lay==0) ? (8+26) : 60)*1024;
        bf16x8 ga[2][2];
        for (int ch=0; ch<8; ++ch){
            LD16(wB, gs8 + (size_t)(8 + lay*26 + 10 + ch*2 + 1)*1024);  // F2[ch]
            F1_BODY(ch, wA);
            LDS_FENCE();             // gt writes -> ga reads
            #pragma unroll
            for (int mt=0;mt<2;++mt)
                #pragma unroll
                for (int ks=0;ks<2;++ks)
                    ga[mt][ks] = *(const bf16x8*)&tile[wv][mt*16+c][ks*32+g*8];
            LDS_FENCE();             // ga reads -> next gt writes (WAR)
            if (ch < 7) LD16(wA, gs8 + (size_t)(8 + lay*26 + 10 + (ch+1)*2)*1024);
            else        LD16(wA, nxsec);   // chain: next layer QKV0 / comb0
            F2_BODY(wB);
        }
        #pragma unroll
        for (int nt2=0;nt2<8;++nt2){
            float bias = (float)prm[P_F2 + lay*128 + nt2*16+c];
            #pragma unroll
            for (int mt=0;mt<2;++mt)
                #pragma unroll
                for (int j=0;j<4;++j) h[mt][nt2][j]+=bias;
        }
    }

    // ---- comb + scatter-mean (wA = sec60, prefetched at lay1 FFN tail)
    #pragma unroll
    for (int mt=0;mt<2;++mt)
        #pragma unroll
        for (int n=0;n<8;++n)
            #pragma unroll
            for (int j=0;j<4;++j)
                tile[wv][mt*16+g*4+j][n*16+c] = (bf16)h[mt][n][j];
    LDS_FENCE();                     // h writes -> afc reads
    bf16x8 afc[4][4];
    #pragma unroll
    for (int tk=0;tk<4;++tk)
        #pragma unroll
        for (int ks=0;ks<4;++ks)
            afc[tk][ks] = *(const bf16x8*)&tile[wv][(c&7)*4+tk][ks*32+g*8];
    for (int kp=0; kp<16; ++kp){
        RAW_BAR();                   // per-iteration align: comb runs against the
                                     // atomic-thrashed L2; L1/MSHR merge is worth most here
        const int chk = kp*2;
        LD16(wB, gs8 + (size_t)(60 + chk + 1)*1024);
        COMB_BODY(chk, wA);
        if (chk+2 < 32) LD16(wA, gs8 + (size_t)(60 + chk + 2)*1024);
        COMB_BODY(chk+1, wB);
    }
}

extern "C" void kernel_launch(void* const* d_in, const int* in_sizes, int n_in,
                              void* d_out, int out_size, void* d_ws, size_t ws_size,
                              hipStream_t stream){
    (void)in_sizes; (void)n_in; (void)ws_size;
    const float* x      = (const float*)d_in[0];
    const float* W_emb  = (const float*)d_in[1];
    const float* b_emb  = (const float*)d_in[2];
    const float* ln1_s  = (const float*)d_in[3];
    const float* ln1_b  = (const float*)d_in[4];
    const float* Wqkv   = (const float*)d_in[5];
    const float* bqkv   = (const float*)d_in[6];
    const float* Wo     = (const float*)d_in[7];
    const float* bo     = (const float*)d_in[8];
    const float* ln2_s  = (const float*)d_in[9];
    const float* ln2_b  = (const float*)d_in[10];
    const float* Wf1    = (const float*)d_in[11];
    const float* bf1    = (const float*)d_in[12];
    const float* Wf2    = (const float*)d_in[13];
    const float* bf2    = (const float*)d_in[14];
    const float* W_comb = (const float*)d_in[15];
    const float* b_comb = (const float*)d_in[16];
    float* out = (float*)d_out;

    char* ws = (char*)d_ws;
    size_t off = 0;
    auto alloc = [&](size_t bytes)->char*{
        char* p = ws + off; off = (off + bytes + 255) & ~(size_t)255; return p;
    };
    bf16* wstream = (bf16*) alloc((size_t)NSEC*8192*2);
    int*  flat    = (int*)  alloc((size_t)N_PTS*4);
    int*  cnt     = (int*)  alloc((size_t)NCELL*4);

    hipMemsetAsync(d_out, 0, (size_t)out_size*sizeof(float), stream);
    hipMemsetAsync(cnt, 0, (size_t)NCELL*4, stream);

    repack_kernel<<<(NSEC*8192+255)/256, 256, 0, stream>>>(
        W_emb, Wqkv, Wo, Wf1, Wf2, W_comb, wstream);
    count_kernel<<<(N_PTS+255)/256, 256, 0, stream>>>(x, flat, cnt);

    fused_kernel<<<2048, 256, 0, stream>>>(x, wstream,
        b_emb, bqkv, bo, bf1, bf2, b_comb,
        ln1_s, ln1_b, ln2_s, ln2_b, flat, cnt, out);
}